// Round 1
// baseline (477.054 us; speedup 1.0000x reference)
//
#include <hip/hip_runtime.h>
#include <hip/hip_cooperative_groups.h>

namespace cg = cooperative_groups;

// DSR loss: R_t = sum_i w[t,i]*x[t,i];  A_t = c*A_{t-1} + eta*R_t (c=0.99),
// B_t likewise with R^2;  D_t from (A_prev,B_prev);  out = -sum(D)/B.
//
// R3 structure: single cooperative kernel. Phase A computes R into LDS with
// 16 loads in flight per wave (R2's K1 was latency-bound at 2.7 TB/s with only
// 2 loads outstanding -- VGPR_Count=12 showed full serialization). Phases B-E
// do the parallel linear-recurrence scan entirely on LDS-resident R: no 8 MB
// R round-trip, no inter-kernel drains. Falls back to the proven R2 5-kernel
// pipeline if the cooperative launch is rejected.

#define D_ETA 0.01
#define D_C   (1.0 - D_ETA)
#define D_EPS 1e-8

constexpr int BLOCK = 256;
constexpr int K1_ROWS = 256;         // rows per K1 block (fallback path)
constexpr int CHUNK = 2048;          // rows per scan block
constexpr int LPT   = CHUNK / BLOCK; // 8 rows per thread
constexpr int MAX_COOP_BLOCKS = 1024; // 4 blocks/CU x 256 CU co-residency cap

// Hillis-Steele inclusive scan over 256 affine transforms (m, sA, sB).
__device__ __forceinline__ void block_scan(double& m, double& sA, double& sB,
                                           double* mS, double* aS, double* bS) {
    int tid = threadIdx.x;
    mS[tid] = m; aS[tid] = sA; bS[tid] = sB;
    __syncthreads();
#pragma unroll
    for (int off = 1; off < BLOCK; off <<= 1) {
        double pm = 1.0, pa = 0.0, pb = 0.0;
        if (tid >= off) { pm = mS[tid - off]; pa = aS[tid - off]; pb = bS[tid - off]; }
        __syncthreads();
        if (tid >= off) {
            sA = m * pa + sA;
            sB = m * pb + sB;
            m  = pm * m;
        }
        mS[tid] = m; aS[tid] = sA; bS[tid] = sB;
        __syncthreads();
    }
}

// ================= cooperative single-kernel path =================
__global__ __launch_bounds__(BLOCK, 4) void k_all(
    const float* __restrict__ w, const float* __restrict__ x, int nrows,
    double* __restrict__ blkM, double* __restrict__ blkA, double* __restrict__ blkB,
    double* __restrict__ bsum, float* __restrict__ out)
{
    __shared__ float  Rlds[CHUNK];                       // 8 KB
    __shared__ double mS[BLOCK], aS[BLOCK], bS[BLOCK];   // 6 KB
    __shared__ double wred[BLOCK / 64];

    const int tid = threadIdx.x;
    const int b   = blockIdx.x;
    const int nb  = gridDim.x;
    const long long base = (long long)b * CHUNK;

    // ---- Phase A: dot products -> LDS (no global R) ----
    // 4 consecutive lanes own one row; per pass the wave reads 2x1KB
    // contiguous. Batched 8 passes deep: 16 dwordx4 loads in flight per wave
    // before the first waitcnt (R2's K1 had 2 -> latency-bound at 2.7 TB/s).
    {
        const int q = tid & 3, rsub = tid >> 2;
        const float4* w4 = (const float4*)w;
        const float4* x4 = (const float4*)x;
        if (base + CHUNK <= (long long)nrows) {
            const long long f0 = (base + rsub) * 4 + q; // float4 index
#pragma unroll
            for (int p0 = 0; p0 < 32; p0 += 8) {
                float4 av[8], bv[8];
#pragma unroll
                for (int u = 0; u < 8; ++u) {
                    long long f = f0 + (long long)(p0 + u) * 256; // 64 rows = 256 f4
                    av[u] = w4[f];
                    bv[u] = x4[f];
                }
#pragma unroll
                for (int u = 0; u < 8; ++u) {
                    double p = (double)av[u].x * bv[u].x
                             + (double)av[u].y * bv[u].y
                             + (double)av[u].z * bv[u].z
                             + (double)av[u].w * bv[u].w;
                    p += __shfl_xor(p, 1, 64);
                    p += __shfl_xor(p, 2, 64);
                    if (q == 0) Rlds[(p0 + u) * 64 + rsub] = (float)p;
                }
            }
        } else {
            // tail chunk: guarded, shuffles stay wave-uniform
            for (int p = 0; p < 32; ++p) {
                long long row = base + (long long)p * 64 + rsub;
                double pd = 0.0;
                if (row < (long long)nrows) {
                    long long f = row * 4 + q;
                    float4 a = w4[f], c = x4[f];
                    pd = (double)a.x * c.x + (double)a.y * c.y
                       + (double)a.z * c.z + (double)a.w * c.w;
                }
                pd += __shfl_xor(pd, 1, 64);
                pd += __shfl_xor(pd, 2, 64);
                if (q == 0) Rlds[p * 64 + rsub] = (float)pd;
            }
        }
    }
    __syncthreads();

    // ---- Phase B: per-chunk affine aggregate ----
    float rv[LPT];
    {
        const float4* Rp = (const float4*)&Rlds[tid * LPT]; // 32B-aligned
        float4 u0 = Rp[0], u1 = Rp[1];
        rv[0] = u0.x; rv[1] = u0.y; rv[2] = u0.z; rv[3] = u0.w;
        rv[4] = u1.x; rv[5] = u1.y; rv[6] = u1.z; rv[7] = u1.w;
    }
    long long g0 = base + (long long)tid * LPT;
    long long rem = (long long)nrows - g0;
    int len = rem >= LPT ? LPT : (rem > 0 ? (int)rem : 0);

    double m = 1.0, sA = 0.0, sB = 0.0;
    for (int k = 0; k < len; ++k) {
        double r = (double)rv[k];
        sA = D_C * sA + D_ETA * r;
        sB = D_C * sB + D_ETA * (r * r);
        m *= D_C;
    }
    block_scan(m, sA, sB, mS, aS, bS);
    if (tid == BLOCK - 1) { blkM[b] = m; blkA[b] = sA; blkB[b] = sB; }
    // exclusive within-chunk prefix for this thread (kept in regs across sync)
    double em = 1.0, ea = 0.0, eb = 0.0;
    if (tid > 0) { em = mS[tid - 1]; ea = aS[tid - 1]; eb = bS[tid - 1]; }

    cg::this_grid().sync();

    // ---- Phase C: chunk prefix [0,b) computed per-block (replaces K3) ----
    double A, B;
    {
        double cm = 1.0, ca = 0.0, cb = 0.0;
        const int nseg = b;                       // chunks before mine
        const int K = (nseg + BLOCK - 1) / BLOCK; // <= 4 when nb <= 1024
        int s0 = tid * K;
        int s1 = s0 + K; if (s1 > nseg) s1 = nseg;
        for (int g = s0; g < s1; ++g) {
            double mg = blkM[g], ag = blkA[g], bg = blkB[g];
            ca = mg * ca + ag;   // compose: f_g after current
            cb = mg * cb + bg;
            cm *= mg;
        }
        block_scan(cm, ca, cb, mS, aS, bS);
        double M  = mS[BLOCK - 1];
        double SA = aS[BLOCK - 1];
        double SB = bS[BLOCK - 1];
        double Astart = SA;                 // M*0 + SA
        double Bstart = M * D_EPS + SB;     // M*eps + SB
        A = em * Astart + ea;
        B = em * Bstart + eb;
    }

    // ---- Phase D: replay from LDS-resident R + D-sum ----
    double dsum = 0.0;
    for (int k = 0; k < len; ++k) {
        double r = (double)rv[k];
        double dA = D_ETA * (r - A);
        double dB = D_ETA * (r * r - B);
        double var = B - A * A;
        if (var < D_EPS) var = D_EPS;
        double denom = var * sqrt(var);
        dsum += (B * dA - 0.5 * A * dB) / denom;
        A += dA;
        B += dB;
    }
#pragma unroll
    for (int off = 32; off > 0; off >>= 1) dsum += __shfl_down(dsum, off, 64);
    if ((tid & 63) == 0) wred[tid >> 6] = dsum;
    __syncthreads();
    if (tid == 0) bsum[b] = wred[0] + wred[1] + wred[2] + wred[3];

    cg::this_grid().sync();

    // ---- Phase E: final reduction (block 0), deterministic ----
    if (b == 0) {
        double s = 0.0;
        for (int i = tid; i < nb; i += BLOCK) s += bsum[i];
#pragma unroll
        for (int off = 32; off > 0; off >>= 1) s += __shfl_down(s, off, 64);
        if ((tid & 63) == 0) wred[tid >> 6] = s;
        __syncthreads();
        if (tid == 0)
            out[0] = (float)(-(wred[0] + wred[1] + wred[2] + wred[3]) / (double)nrows);
    }
}

// ================= fallback: proven R2 5-kernel path =================

__device__ __forceinline__ float row_R(const float* __restrict__ w,
                                       const float* __restrict__ x,
                                       long long row) {
    const float4* w4 = (const float4*)(w + row * 16);
    const float4* x4 = (const float4*)(x + row * 16);
    double r = 0.0;
#pragma unroll
    for (int q = 0; q < 4; ++q) {
        float4 a = w4[q];
        float4 b = x4[q];
        r += (double)a.x * (double)b.x;
        r += (double)a.y * (double)b.y;
        r += (double)a.z * (double)b.z;
        r += (double)a.w * (double)b.w;
    }
    return (float)r;
}

__global__ __launch_bounds__(BLOCK) void k1_dots(
    const float* __restrict__ w, const float* __restrict__ x, int nrows,
    float* __restrict__ R)
{
    int tid = threadIdx.x;
    int q    = tid & 3;
    int rsub = tid >> 2;
    long long base = (long long)blockIdx.x * K1_ROWS;
    const float4* w4 = (const float4*)w;
    const float4* x4 = (const float4*)x;
#pragma unroll
    for (int it = 0; it < K1_ROWS / 64; ++it) {
        long long row = base + (long long)it * 64 + rsub;
        if (row < nrows) {
            long long f = row * 4 + q;
            float4 a = w4[f];
            float4 b = x4[f];
            double p = (double)a.x * (double)b.x
                     + (double)a.y * (double)b.y
                     + (double)a.z * (double)b.z
                     + (double)a.w * (double)b.w;
            p += __shfl_xor(p, 1, 64);
            p += __shfl_xor(p, 2, 64);
            if (q == 0) R[row] = (float)p;
        }
    }
}

__device__ __forceinline__ int load_seg(const float* __restrict__ Rws,
                                        const float* __restrict__ w,
                                        const float* __restrict__ x,
                                        long long g0, int nrows, float* rv) {
    long long rem = (long long)nrows - g0;
    int len = rem >= LPT ? LPT : (rem > 0 ? (int)rem : 0);
    if (Rws) {
        if (len == LPT) {
            const float4* Rp = (const float4*)(Rws + g0);
            float4 u = Rp[0], v = Rp[1];
            rv[0]=u.x; rv[1]=u.y; rv[2]=u.z; rv[3]=u.w;
            rv[4]=v.x; rv[5]=v.y; rv[6]=v.z; rv[7]=v.w;
        } else {
            for (int k = 0; k < len; ++k) rv[k] = Rws[g0 + k];
        }
    } else {
        for (int k = 0; k < len; ++k) rv[k] = row_R(w, x, g0 + k);
    }
    return len;
}

__global__ __launch_bounds__(BLOCK) void k2_partials(
    const float* __restrict__ Rws,
    const float* __restrict__ w, const float* __restrict__ x, int nrows,
    double* __restrict__ blkM, double* __restrict__ blkA, double* __restrict__ blkB)
{
    __shared__ double mS[BLOCK], aS[BLOCK], bS[BLOCK];
    int tid = threadIdx.x;
    long long g0 = (long long)blockIdx.x * CHUNK + (long long)tid * LPT;
    float rv[LPT];
    int len = load_seg(Rws, w, x, g0, nrows, rv);

    double m = 1.0, sA = 0.0, sB = 0.0;
    for (int k = 0; k < len; ++k) {
        double r = (double)rv[k];
        sA = D_C * sA + D_ETA * r;
        sB = D_C * sB + D_ETA * (r * r);
        m *= D_C;
    }
    block_scan(m, sA, sB, mS, aS, bS);
    if (tid == BLOCK - 1) {
        blkM[blockIdx.x] = m;
        blkA[blockIdx.x] = sA;
        blkB[blockIdx.x] = sB;
    }
}

__global__ __launch_bounds__(BLOCK) void k3_scan(
    int nb,
    const double* __restrict__ blkM, const double* __restrict__ blkA,
    const double* __restrict__ blkB,
    double* __restrict__ A0, double* __restrict__ B0)
{
    __shared__ double mS[BLOCK], aS[BLOCK], bS[BLOCK];
    int tid = threadIdx.x;
    int K = (nb + BLOCK - 1) / BLOCK;
    int g0 = tid * K;
    int g1 = g0 + K; if (g1 > nb) g1 = nb;

    double m = 1.0, sA = 0.0, sB = 0.0;
    for (int g = g0; g < g1; ++g) {
        double mg = blkM[g], ag = blkA[g], bg = blkB[g];
        sA = mg * sA + ag;
        sB = mg * sB + bg;
        m *= mg;
    }
    block_scan(m, sA, sB, mS, aS, bS);

    double em = 1.0, ea = 0.0, eb = 0.0;
    if (tid > 0) { em = mS[tid - 1]; ea = aS[tid - 1]; eb = bS[tid - 1]; }
    double A = ea;
    double B = em * D_EPS + eb;
    for (int g = g0; g < g1; ++g) {
        A0[g] = A; B0[g] = B;
        double mg = blkM[g], ag = blkA[g], bg = blkB[g];
        A = mg * A + ag;
        B = mg * B + bg;
    }
}

__global__ __launch_bounds__(BLOCK) void k4_dsum(
    const float* __restrict__ Rws,
    const float* __restrict__ w, const float* __restrict__ x, int nrows,
    const double* __restrict__ A0, const double* __restrict__ B0,
    double* __restrict__ bsum)
{
    __shared__ double mS[BLOCK], aS[BLOCK], bS[BLOCK];
    __shared__ double wsum[BLOCK / 64];
    int tid = threadIdx.x;
    long long g0 = (long long)blockIdx.x * CHUNK + (long long)tid * LPT;
    float rv[LPT];
    int len = load_seg(Rws, w, x, g0, nrows, rv);

    double m = 1.0, sA = 0.0, sB = 0.0;
    for (int k = 0; k < len; ++k) {
        double r = (double)rv[k];
        sA = D_C * sA + D_ETA * r;
        sB = D_C * sB + D_ETA * (r * r);
        m *= D_C;
    }
    block_scan(m, sA, sB, mS, aS, bS);

    double em = 1.0, ea = 0.0, eb = 0.0;
    if (tid > 0) { em = mS[tid - 1]; ea = aS[tid - 1]; eb = bS[tid - 1]; }
    double A = em * A0[blockIdx.x] + ea;
    double B = em * B0[blockIdx.x] + eb;

    double dsum = 0.0;
    for (int k = 0; k < len; ++k) {
        double r = (double)rv[k];
        double dA = D_ETA * (r - A);
        double dB = D_ETA * (r * r - B);
        double var = B - A * A;
        if (var < D_EPS) var = D_EPS;
        double denom = var * sqrt(var);
        dsum += (B * dA - 0.5 * A * dB) / denom;
        A += dA;
        B += dB;
    }

#pragma unroll
    for (int off = 32; off > 0; off >>= 1) dsum += __shfl_down(dsum, off, 64);
    if ((tid & 63) == 0) wsum[tid >> 6] = dsum;
    __syncthreads();
    if (tid == 0) bsum[blockIdx.x] = wsum[0] + wsum[1] + wsum[2] + wsum[3];
}

__global__ __launch_bounds__(BLOCK) void k5_final(
    const double* __restrict__ bsum, int nb, int nrows, float* __restrict__ out)
{
    __shared__ double sh[BLOCK / 64];
    int tid = threadIdx.x;
    double s = 0.0;
    for (int i = tid; i < nb; i += BLOCK) s += bsum[i];
#pragma unroll
    for (int off = 32; off > 0; off >>= 1) s += __shfl_down(s, off, 64);
    if ((tid & 63) == 0) sh[tid >> 6] = s;
    __syncthreads();
    if (tid == 0) out[0] = (float)(-(sh[0] + sh[1] + sh[2] + sh[3]) / (double)nrows);
}

extern "C" void kernel_launch(void* const* d_in, const int* in_sizes, int n_in,
                              void* d_out, int out_size, void* d_ws, size_t ws_size,
                              hipStream_t stream)
{
    const float* w = (const float*)d_in[0];
    const float* x = (const float*)d_in[1];
    int nrows = in_sizes[0] / 16;
    int nb  = (nrows + CHUNK - 1) / CHUNK;
    int nb1 = (nrows + K1_ROWS - 1) / K1_ROWS;

    char* ws = (char*)d_ws;
    double* blkM = (double*)(ws + 64);
    double* blkA = blkM + nb;
    double* blkB = blkA + nb;
    double* A0   = blkB + nb;
    double* B0   = A0 + nb;
    double* bsum = B0 + nb;

    // ---- preferred: single cooperative kernel ----
    if (nb >= 1 && nb <= MAX_COOP_BLOCKS &&
        ws_size >= 64 + (size_t)6 * nb * sizeof(double)) {
        float* outp = (float*)d_out;
        void* args[] = { (void*)&w, (void*)&x, (void*)&nrows,
                         (void*)&blkM, (void*)&blkA, (void*)&blkB,
                         (void*)&bsum, (void*)&outp };
        hipError_t e = hipLaunchCooperativeKernel((const void*)k_all,
                                                  dim3(nb), dim3(BLOCK),
                                                  args, 0, stream);
        if (e == hipSuccess) return;
        (void)hipGetLastError(); // clear and fall back
    }

    // ---- fallback: R2 pipeline ----
    size_t off = 64 + (size_t)6 * nb * sizeof(double);
    off = (off + 255) & ~(size_t)255;
    float* Rws = nullptr;
    if (ws_size >= off + (size_t)nrows * sizeof(float))
        Rws = (float*)(ws + off);

    if (Rws)
        k1_dots<<<nb1, BLOCK, 0, stream>>>(w, x, nrows, Rws);
    k2_partials<<<nb, BLOCK, 0, stream>>>(Rws, w, x, nrows, blkM, blkA, blkB);
    k3_scan<<<1, BLOCK, 0, stream>>>(nb, blkM, blkA, blkB, A0, B0);
    k4_dsum<<<nb, BLOCK, 0, stream>>>(Rws, w, x, nrows, A0, B0, bsum);
    k5_final<<<1, BLOCK, 0, stream>>>(bsum, nb, nrows, (float*)d_out);
}

// Round 2
// 286.809 us; speedup vs baseline: 1.6633x; 1.6633x over previous
//
#include <hip/hip_runtime.h>

// DSR loss: R_t = sum_i w[t,i]*x[t,i];  A_t = c*A_{t-1} + eta*R_t (c=0.99),
// B_t likewise with R^2;  D_t from (A_prev,B_prev);  out = -sum(D)/B.
//
// R4 structure: back to plain multi-kernel (coop grid-sync regressed, R3).
// k1_fused = K1+K2: per 2048-row chunk, compute R with 16 wave-loads in
// flight (sched_barrier(0) fence defeats the scheduler's load-sinking that
// produced VGPR=44 in R3), LDS round-trip to thread-owns-8-rows order,
// single coalesced R write, chunk affine aggregate in the same kernel.
// K3 (chunk-prefix scan), K4 (replay + D-sum), K5 (reduce) unchanged from
// the proven R2 pipeline; numerics bit-identical throughout.

#define D_ETA 0.01
#define D_C   (1.0 - D_ETA)
#define D_EPS 1e-8

constexpr int BLOCK = 256;
constexpr int CHUNK = 2048;          // rows per block
constexpr int LPT   = CHUNK / BLOCK; // 8 rows per thread
constexpr int PASSES = CHUNK / 64;   // 32 passes of 64 rows
constexpr int BATCH  = 8;            // passes per load-batch: 16 loads in flight

// Hillis-Steele inclusive scan over 256 affine transforms (m, sA, sB).
__device__ __forceinline__ void block_scan(double& m, double& sA, double& sB,
                                           double* mS, double* aS, double* bS) {
    int tid = threadIdx.x;
    mS[tid] = m; aS[tid] = sA; bS[tid] = sB;
    __syncthreads();
#pragma unroll
    for (int off = 1; off < BLOCK; off <<= 1) {
        double pm = 1.0, pa = 0.0, pb = 0.0;
        if (tid >= off) { pm = mS[tid - off]; pa = aS[tid - off]; pb = bS[tid - off]; }
        __syncthreads();
        if (tid >= off) {
            sA = m * pa + sA;
            sB = m * pb + sB;
            m  = pm * m;
        }
        mS[tid] = m; aS[tid] = sA; bS[tid] = sB;
        __syncthreads();
    }
}

// ---------------- K1': dots + chunk aggregate (fused K1+K2) ----------------
// Phase A: 4 consecutive lanes own one row; per pass each wave issues 2
// perfectly-coalesced 1KB loads. 8 passes are batched: 16 loads issued, then
// sched_barrier(0) so the scheduler cannot sink them into the consume loop
// (R3's failure mode: VGPR=44 proved it had re-serialized to ~4 in flight).
// Phase B: LDS round-trip to per-thread-8-consecutive-rows order, one
// coalesced global R write, then the chunk affine aggregate (old K2).
__global__ __launch_bounds__(BLOCK, 4) void k1_fused(
    const float* __restrict__ w, const float* __restrict__ x, int nrows,
    float* __restrict__ Rws,
    double* __restrict__ blkM, double* __restrict__ blkA, double* __restrict__ blkB)
{
    __shared__ float  Rlds[CHUNK];                     // 8 KB
    __shared__ double mS[BLOCK], aS[BLOCK], bS[BLOCK]; // 6 KB

    const int tid = threadIdx.x;
    const int b   = blockIdx.x;
    const long long base = (long long)b * CHUNK;
    const int q    = tid & 3;
    const int rsub = tid >> 2;
    const float4* w4 = (const float4*)w;
    const float4* x4 = (const float4*)x;

    const bool full = (base + CHUNK <= (long long)nrows);

    if (full) {
        // f index for pass p: base*4 + tid + p*256  (contiguous across tid)
        const long long f0 = base * 4 + tid;
        for (int p0 = 0; p0 < PASSES; p0 += BATCH) {
            float4 av[BATCH], bv[BATCH];
#pragma unroll
            for (int u = 0; u < BATCH; ++u) {
                const long long f = f0 + (long long)(p0 + u) * 256;
                av[u] = w4[f];
                bv[u] = x4[f];
            }
            __builtin_amdgcn_sched_barrier(0); // all 16 loads issued before any use
#pragma unroll
            for (int u = 0; u < BATCH; ++u) {
                double p = (double)av[u].x * bv[u].x
                         + (double)av[u].y * bv[u].y
                         + (double)av[u].z * bv[u].z
                         + (double)av[u].w * bv[u].w;
                p += __shfl_xor(p, 1, 64);
                p += __shfl_xor(p, 2, 64);
                if (q == 0) Rlds[(p0 + u) * 64 + rsub] = (float)p;
            }
        }
    } else {
        // tail chunk: guarded, shuffles stay wave-uniform
        for (int p = 0; p < PASSES; ++p) {
            long long row = base + (long long)p * 64 + rsub;
            double pd = 0.0;
            if (row < (long long)nrows) {
                long long f = row * 4 + q;
                float4 a = w4[f], c = x4[f];
                pd = (double)a.x * c.x + (double)a.y * c.y
                   + (double)a.z * c.z + (double)a.w * c.w;
            }
            pd += __shfl_xor(pd, 1, 64);
            pd += __shfl_xor(pd, 2, 64);
            if (q == 0) Rlds[p * 64 + rsub] = (float)pd;
        }
    }
    __syncthreads();

    // ---- Phase B: redistribute, persist R, chunk aggregate ----
    float rv[LPT];
    {
        const float4* Rp = (const float4*)&Rlds[tid * LPT]; // 32B-aligned
        float4 u0 = Rp[0], u1 = Rp[1];
        rv[0] = u0.x; rv[1] = u0.y; rv[2] = u0.z; rv[3] = u0.w;
        rv[4] = u1.x; rv[5] = u1.y; rv[6] = u1.z; rv[7] = u1.w;
    }
    long long g0 = base + (long long)tid * LPT;
    long long rem = (long long)nrows - g0;
    int len = rem >= LPT ? LPT : (rem > 0 ? (int)rem : 0);

    if (len == LPT) {
        float4* Rp = (float4*)(Rws + g0);
        Rp[0] = make_float4(rv[0], rv[1], rv[2], rv[3]);
        Rp[1] = make_float4(rv[4], rv[5], rv[6], rv[7]);
    } else {
        for (int k = 0; k < len; ++k) Rws[g0 + k] = rv[k];
    }

    double m = 1.0, sA = 0.0, sB = 0.0;
    for (int k = 0; k < len; ++k) {
        double r = (double)rv[k];
        sA = D_C * sA + D_ETA * r;
        sB = D_C * sB + D_ETA * (r * r);
        m *= D_C;
    }
    block_scan(m, sA, sB, mS, aS, bS);
    if (tid == BLOCK - 1) {
        blkM[b] = m;
        blkA[b] = sA;
        blkB[b] = sB;
    }
}

// ---------------- fallback helpers (ws too small: recompute R) -------------
__device__ __forceinline__ float row_R(const float* __restrict__ w,
                                       const float* __restrict__ x,
                                       long long row) {
    const float4* w4 = (const float4*)(w + row * 16);
    const float4* x4 = (const float4*)(x + row * 16);
    double r = 0.0;
#pragma unroll
    for (int q = 0; q < 4; ++q) {
        float4 a = w4[q];
        float4 b = x4[q];
        r += (double)a.x * (double)b.x;
        r += (double)a.y * (double)b.y;
        r += (double)a.z * (double)b.z;
        r += (double)a.w * (double)b.w;
    }
    return (float)r;
}

__device__ __forceinline__ int load_seg(const float* __restrict__ Rws,
                                        const float* __restrict__ w,
                                        const float* __restrict__ x,
                                        long long g0, int nrows, float* rv) {
    long long rem = (long long)nrows - g0;
    int len = rem >= LPT ? LPT : (rem > 0 ? (int)rem : 0);
    if (Rws) {
        if (len == LPT) {
            const float4* Rp = (const float4*)(Rws + g0);
            float4 u = Rp[0], v = Rp[1];
            rv[0]=u.x; rv[1]=u.y; rv[2]=u.z; rv[3]=u.w;
            rv[4]=v.x; rv[5]=v.y; rv[6]=v.z; rv[7]=v.w;
        } else {
            for (int k = 0; k < len; ++k) rv[k] = Rws[g0 + k];
        }
    } else {
        for (int k = 0; k < len; ++k) rv[k] = row_R(w, x, g0 + k);
    }
    return len;
}

// ---------------- K2 (fallback only): per-chunk affine aggregates ----------
__global__ __launch_bounds__(BLOCK) void k2_partials(
    const float* __restrict__ Rws,
    const float* __restrict__ w, const float* __restrict__ x, int nrows,
    double* __restrict__ blkM, double* __restrict__ blkA, double* __restrict__ blkB)
{
    __shared__ double mS[BLOCK], aS[BLOCK], bS[BLOCK];
    int tid = threadIdx.x;
    long long g0 = (long long)blockIdx.x * CHUNK + (long long)tid * LPT;
    float rv[LPT];
    int len = load_seg(Rws, w, x, g0, nrows, rv);

    double m = 1.0, sA = 0.0, sB = 0.0;
    for (int k = 0; k < len; ++k) {
        double r = (double)rv[k];
        sA = D_C * sA + D_ETA * r;
        sB = D_C * sB + D_ETA * (r * r);
        m *= D_C;
    }
    block_scan(m, sA, sB, mS, aS, bS);
    if (tid == BLOCK - 1) {
        blkM[blockIdx.x] = m;
        blkA[blockIdx.x] = sA;
        blkB[blockIdx.x] = sB;
    }
}

// ---------------- K3: scan of chunk aggregates (1 block) ----------------
__global__ __launch_bounds__(BLOCK) void k3_scan(
    int nb,
    const double* __restrict__ blkM, const double* __restrict__ blkA,
    const double* __restrict__ blkB,
    double* __restrict__ A0, double* __restrict__ B0)
{
    __shared__ double mS[BLOCK], aS[BLOCK], bS[BLOCK];
    int tid = threadIdx.x;
    int K = (nb + BLOCK - 1) / BLOCK;
    int g0 = tid * K;
    int g1 = g0 + K; if (g1 > nb) g1 = nb;

    double m = 1.0, sA = 0.0, sB = 0.0;
    for (int g = g0; g < g1; ++g) {
        double mg = blkM[g], ag = blkA[g], bg = blkB[g];
        sA = mg * sA + ag;
        sB = mg * sB + bg;
        m *= mg;
    }
    block_scan(m, sA, sB, mS, aS, bS);

    double em = 1.0, ea = 0.0, eb = 0.0;
    if (tid > 0) { em = mS[tid - 1]; ea = aS[tid - 1]; eb = bS[tid - 1]; }
    double A = ea;                 // em*0 + ea
    double B = em * D_EPS + eb;
    for (int g = g0; g < g1; ++g) {
        A0[g] = A; B0[g] = B;
        double mg = blkM[g], ag = blkA[g], bg = blkB[g];
        A = mg * A + ag;
        B = mg * B + bg;
    }
}

// ---------------- K4: replay + D sum ----------------
__global__ __launch_bounds__(BLOCK) void k4_dsum(
    const float* __restrict__ Rws,
    const float* __restrict__ w, const float* __restrict__ x, int nrows,
    const double* __restrict__ A0, const double* __restrict__ B0,
    double* __restrict__ bsum)
{
    __shared__ double mS[BLOCK], aS[BLOCK], bS[BLOCK];
    __shared__ double wsum[BLOCK / 64];
    int tid = threadIdx.x;
    long long g0 = (long long)blockIdx.x * CHUNK + (long long)tid * LPT;
    float rv[LPT];
    int len = load_seg(Rws, w, x, g0, nrows, rv);

    double m = 1.0, sA = 0.0, sB = 0.0;
    for (int k = 0; k < len; ++k) {
        double r = (double)rv[k];
        sA = D_C * sA + D_ETA * r;
        sB = D_C * sB + D_ETA * (r * r);
        m *= D_C;
    }
    block_scan(m, sA, sB, mS, aS, bS);

    double em = 1.0, ea = 0.0, eb = 0.0;
    if (tid > 0) { em = mS[tid - 1]; ea = aS[tid - 1]; eb = bS[tid - 1]; }
    double A = em * A0[blockIdx.x] + ea;
    double B = em * B0[blockIdx.x] + eb;

    double dsum = 0.0;
    for (int k = 0; k < len; ++k) {
        double r = (double)rv[k];
        double dA = D_ETA * (r - A);
        double dB = D_ETA * (r * r - B);
        double var = B - A * A;
        if (var < D_EPS) var = D_EPS;
        double denom = var * sqrt(var);
        dsum += (B * dA - 0.5 * A * dB) / denom;
        A += dA;
        B += dB;
    }

#pragma unroll
    for (int off = 32; off > 0; off >>= 1) dsum += __shfl_down(dsum, off, 64);
    if ((tid & 63) == 0) wsum[tid >> 6] = dsum;
    __syncthreads();
    if (tid == 0) bsum[blockIdx.x] = wsum[0] + wsum[1] + wsum[2] + wsum[3];
}

// ---------------- K5: final reduction ----------------
__global__ __launch_bounds__(BLOCK) void k5_final(
    const double* __restrict__ bsum, int nb, int nrows, float* __restrict__ out)
{
    __shared__ double sh[BLOCK / 64];
    int tid = threadIdx.x;
    double s = 0.0;
    for (int i = tid; i < nb; i += BLOCK) s += bsum[i];
#pragma unroll
    for (int off = 32; off > 0; off >>= 1) s += __shfl_down(s, off, 64);
    if ((tid & 63) == 0) sh[tid >> 6] = s;
    __syncthreads();
    if (tid == 0) out[0] = (float)(-(sh[0] + sh[1] + sh[2] + sh[3]) / (double)nrows);
}

extern "C" void kernel_launch(void* const* d_in, const int* in_sizes, int n_in,
                              void* d_out, int out_size, void* d_ws, size_t ws_size,
                              hipStream_t stream)
{
    const float* w = (const float*)d_in[0];
    const float* x = (const float*)d_in[1];
    int nrows = in_sizes[0] / 16;
    int nb  = (nrows + CHUNK - 1) / CHUNK;

    char* ws = (char*)d_ws;
    double* blkM = (double*)(ws + 64);
    double* blkA = blkM + nb;
    double* blkB = blkA + nb;
    double* A0   = blkB + nb;
    double* B0   = A0 + nb;
    double* bsum = B0 + nb;

    size_t off = 64 + (size_t)6 * nb * sizeof(double);
    off = (off + 255) & ~(size_t)255;
    float* Rws = nullptr;
    if (ws_size >= off + (size_t)nrows * sizeof(float))
        Rws = (float*)(ws + off);

    if (Rws) {
        // fused K1+K2: single pass over w,x; R persisted once
        k1_fused<<<nb, BLOCK, 0, stream>>>(w, x, nrows, Rws, blkM, blkA, blkB);
    } else {
        k2_partials<<<nb, BLOCK, 0, stream>>>(Rws, w, x, nrows, blkM, blkA, blkB);
    }
    k3_scan<<<1, BLOCK, 0, stream>>>(nb, blkM, blkA, blkB, A0, B0);
    k4_dsum<<<nb, BLOCK, 0, stream>>>(Rws, w, x, nrows, A0, B0, bsum);
    k5_final<<<1, BLOCK, 0, stream>>>(bsum, nb, nrows, (float*)d_out);
}